// Round 8
// baseline (264.174 us; speedup 1.0000x reference)
//
#include <hip/hip_runtime.h>
#include <hip/hip_bf16.h>
#include <math.h>

// AdaptiveContrastiveLoss: x[4096][512] f32 -> scalar f32.
// R7: exploit sim symmetry — compute only upper-triangular tiles (528 of
// 1024 blocks), weight strictly-upper tiles x2 (bitwise-equal mirrors, so
// the exact multiset is preserved; weight-2 boundary candidates appended
// twice). NB 4096->2048, LCAP->512 to cut LDS to 41-45KB -> 3 blocks/CU.
// ws: xnb 4MB | pcand 1MB | ncand 1MB | Meta ~8.3KB.

#define N 4096
#define D 512
#define NN 16777216u
#define NB 2048          // uniform value bins
#define CAND_CAP 262144  // per-side global candidate capacity (1MB)
#define LCAP 512         // per-block LDS candidate capacity (expect ~200/block)

typedef __attribute__((ext_vector_type(8))) short bf16x8;
typedef __attribute__((ext_vector_type(4))) float f32x4;

struct Meta {
  unsigned int hist[NB];
  unsigned int bp, rwp;      // pos threshold bin + rank within bin
  unsigned int bn_, rwn;     // neg threshold bin + rank within bin
  unsigned int pcCnt, ncCnt; // candidate counts
  unsigned int pcnt, ncnt;   // strict mask counts
  double psum, nsum;         // strict mask numerators
};

// monotone value->bin: floor((s+1)*1024), clamped. identical math everywhere.
__device__ __forceinline__ int val2bin(float s) {
  int b = (int)fmaf(s, 1024.0f, 1024.0f);
  return b < 0 ? 0 : (b > NB - 1 ? NB - 1 : b);
}
__device__ __forceinline__ unsigned int f2key(float f) {
  unsigned int u = __float_as_uint(f);
  return (u & 0x80000000u) ? ~u : (u | 0x80000000u);
}
__device__ __forceinline__ float key2f(unsigned int k) {
  unsigned int u = (k & 0x80000000u) ? (k ^ 0x80000000u) : ~k;
  return __uint_as_float(u);
}
__device__ __forceinline__ unsigned short f2bf(float f) {  // RNE
  unsigned int u = __float_as_uint(f);
  u += 0x7FFFu + ((u >> 16) & 1u);
  return (unsigned short)(u >> 16);
}

// ---- 1) row norms + normalize + f32->bf16 convert ----
__global__ __launch_bounds__(256) void norm_conv(const float* __restrict__ x,
                                                 unsigned short* __restrict__ xnb) {
  const int row = blockIdx.x;
  const int tid = threadIdx.x;
  const float2 v = ((const float2*)(x + (size_t)row * D))[tid];
  float s = v.x * v.x + v.y * v.y;
#pragma unroll
  for (int o = 32; o > 0; o >>= 1) s += __shfl_xor(s, o);
  __shared__ float wsum[4];
  __shared__ float s_rinv;
  if ((tid & 63) == 0) wsum[tid >> 6] = s;
  __syncthreads();
  if (tid == 0) {
    float t = wsum[0] + wsum[1] + wsum[2] + wsum[3];
    s_rinv = 1.0f / fmaxf(sqrtf(t), 1e-8f);
  }
  __syncthreads();
  const float r = s_rinv;
  ((ushort2*)(xnb + (size_t)row * D))[tid] = make_ushort2(f2bf(v.x * r), f2bf(v.y * r));
}

// ---- shared GEMM tile core: 128x128 tile, 4 waves, acc[4][4] f32x4/lane ----
#define BM 128
#define BK 64
#define LDK 72  // padded row stride (144B: 16B-aligned, 2-way-bank free)
__device__ __forceinline__ void compute_tile(const unsigned short* __restrict__ xnb,
                                             unsigned short As[BM][LDK],
                                             unsigned short Bs[BM][LDK],
                                             int bm, int bn, int tid,
                                             f32x4 acc[4][4]) {
  const int w = tid >> 6, l = tid & 63;
  const int wr = w >> 1, wc = w & 1;
  const int lr = l & 15, lk = (l >> 4) * 8;
  const int srow = tid >> 3;        // 0..31
  const int skoff = (tid & 7) * 8;  // 0..56

  for (int kt = 0; kt < D; kt += BK) {
    bf16x8 av[4], bv[4];
#pragma unroll
    for (int r4 = 0; r4 < 4; ++r4) {
      const int row = srow + r4 * 32;
      av[r4] = *(const bf16x8*)&xnb[(size_t)(bm + row) * D + kt + skoff];
      bv[r4] = *(const bf16x8*)&xnb[(size_t)(bn + row) * D + kt + skoff];
    }
    __syncthreads();
#pragma unroll
    for (int r4 = 0; r4 < 4; ++r4) {
      const int row = srow + r4 * 32;
      *(bf16x8*)&As[row][skoff] = av[r4];
      *(bf16x8*)&Bs[row][skoff] = bv[r4];
    }
    __syncthreads();
#pragma unroll
    for (int kk = 0; kk < BK; kk += 32) {
      bf16x8 af[4], bf[4];
#pragma unroll
      for (int m = 0; m < 4; ++m)
        af[m] = *(const bf16x8*)&As[wr * 64 + m * 16 + lr][kk + lk];
#pragma unroll
      for (int n = 0; n < 4; ++n)
        bf[n] = *(const bf16x8*)&Bs[wc * 64 + n * 16 + lr][kk + lk];
#pragma unroll
      for (int m = 0; m < 4; ++m)
#pragma unroll
        for (int n = 0; n < 4; ++n)
          acc[m][n] = __builtin_amdgcn_mfma_f32_16x16x32_bf16(af[m], bf[n], acc[m][n], 0, 0, 0);
    }
  }
}

// ---- 2) GEMM pass A (upper triangle only): weighted tile histogram ----
__global__ __launch_bounds__(256) void gemm_hist(const unsigned short* __restrict__ xnb,
                                                 Meta* __restrict__ mt) {
  if (blockIdx.x > blockIdx.y) return;  // lower-triangle tiles: mirrors of upper
  __shared__ unsigned short As[BM][LDK];
  __shared__ unsigned short Bs[BM][LDK];
  __shared__ unsigned int h[NB];
  const int tid = threadIdx.x;
  const unsigned int wgt = (blockIdx.x == blockIdx.y) ? 1u : 2u;
  for (int i = tid; i < NB; i += 256) h[i] = 0;

  f32x4 acc[4][4] = {};
  compute_tile(xnb, As, Bs, blockIdx.x * BM, blockIdx.y * BM, tid, acc);

  __syncthreads();
#pragma unroll
  for (int m = 0; m < 4; ++m)
#pragma unroll
    for (int n = 0; n < 4; ++n)
#pragma unroll
      for (int e = 0; e < 4; ++e)
        atomicAdd(&h[val2bin(acc[m][n][e])], wgt);
  __syncthreads();
  for (int i = tid; i < NB; i += 256) {
    const unsigned int c = h[i];
    if (c) atomicAdd(&mt->hist[i], c);
  }
}

// ---- 3) threshold bins + ranks: parallel prefix, owner-thread resolve ----
__global__ __launch_bounds__(256) void scan_bins(Meta* __restrict__ m,
                                                 unsigned int kneg, unsigned int kpos) {
  __shared__ unsigned int part[256], Q[256];
  __shared__ unsigned int res_b[2], res_r[2];
  const int tid = threadIdx.x;
  if (tid < 2) { res_b[tid] = NB - 1; res_r[tid] = 0; }  // safe defaults
  const unsigned int base = tid * (NB / 256);
  unsigned int loc[NB / 256];
  unsigned int s = 0;
#pragma unroll
  for (int i = 0; i < NB / 256; ++i) { loc[i] = m->hist[base + i]; s += loc[i]; }
  part[tid] = s;
  Q[tid] = s;
  __syncthreads();
#pragma unroll
  for (int off = 1; off < 256; off <<= 1) {
    unsigned int t = (tid >= off) ? Q[tid - off] : 0u;
    __syncthreads();
    Q[tid] += t;
    __syncthreads();
  }
  const unsigned int total = Q[255];
  const unsigned int incl = Q[tid];
  const unsigned int excl = incl - part[tid];
  const unsigned int targets[2] = {kpos, kneg};
#pragma unroll
  for (int t = 0; t < 2; ++t) {
    // clamp: owner guaranteed whenever total > 0
    const unsigned int r = (total == 0u) ? 0u
                         : (targets[t] < total ? targets[t] : total - 1u);
    if (total != 0u && excl <= r && r < incl) {  // exactly one owner thread
      unsigned int rr = r - excl, cum = 0;
      int bsel = -1;
#pragma unroll
      for (int i = 0; i < NB / 256; ++i) {
        if (bsel < 0 && cum + loc[i] > rr) bsel = i;
        else if (bsel < 0) cum += loc[i];
      }
      if (bsel < 0) bsel = NB / 256 - 1;
      res_b[t] = base + (unsigned int)bsel;
      res_r[t] = rr - cum;
    }
  }
  __syncthreads();
  if (tid == 0) {
    m->bp = res_b[0]; m->rwp = res_r[0];
    m->bn_ = res_b[1]; m->rwn = res_r[1];
  }
}

// ---- 4) GEMM pass B (upper triangle only): weighted strict loss +
//         boundary-bin candidate compaction (weight-2 appended twice) ----
__global__ __launch_bounds__(256) void gemm_loss(const unsigned short* __restrict__ xnb,
                                                 Meta* __restrict__ mt,
                                                 float* __restrict__ pcand,
                                                 float* __restrict__ ncand) {
  if (blockIdx.x > blockIdx.y) return;
  __shared__ unsigned short As[BM][LDK];
  __shared__ unsigned short Bs[BM][LDK];
  __shared__ float lp[LCAP], ln[LCAP];
  __shared__ unsigned int lpc, lnc, pbase, nbase;
  const int tid = threadIdx.x;
  const unsigned int wgt = (blockIdx.x == blockIdx.y) ? 1u : 2u;
  if (tid == 0) { lpc = 0; lnc = 0; }

  f32x4 acc[4][4] = {};
  compute_tile(xnb, As, Bs, blockIdx.x * BM, blockIdx.y * BM, tid, acc);

  const unsigned int bp = mt->bp, bn = mt->bn_;
  float ps = 0.f, ns = 0.f;
  unsigned int pc = 0, nc = 0;
  const float fw = (float)wgt;
#pragma unroll
  for (int m = 0; m < 4; ++m)
#pragma unroll
    for (int n = 0; n < 4; ++n)
#pragma unroll
      for (int e = 0; e < 4; ++e) {
        const float s = acc[m][n][e];
        const unsigned int b = (unsigned int)val2bin(s);
        if (b > bp) { pc += wgt; ps += fw * fmaxf(1.0f - s, 0.0f); }
        else if (b == bp) {
          const unsigned int i = atomicAdd(&lpc, wgt);
          if (i < LCAP) lp[i] = s;
          if (wgt == 2u && i + 1u < LCAP) lp[i + 1u] = s;
        }
        if (b < bn) { nc += wgt; ns += fw * fmaxf(s, 0.0f); }
        else if (b == bn) {
          const unsigned int i = atomicAdd(&lnc, wgt);
          if (i < LCAP) ln[i] = s;
          if (wgt == 2u && i + 1u < LCAP) ln[i + 1u] = s;
        }
      }
  double psd = ps, nsd = ns;
#pragma unroll
  for (int o = 32; o > 0; o >>= 1) {
    psd += __shfl_xor(psd, o);
    nsd += __shfl_xor(nsd, o);
    pc += __shfl_xor(pc, o);
    nc += __shfl_xor(nc, o);
  }
  __shared__ double sps[4], sns[4];
  __shared__ unsigned int spc[4], snc[4];
  if ((tid & 63) == 0) { const int w = tid >> 6; sps[w] = psd; sns[w] = nsd; spc[w] = pc; snc[w] = nc; }
  __syncthreads();
  if (tid == 0) {
    atomicAdd(&mt->psum, sps[0] + sps[1] + sps[2] + sps[3]);
    atomicAdd(&mt->nsum, sns[0] + sns[1] + sns[2] + sns[3]);
    atomicAdd(&mt->pcnt, spc[0] + spc[1] + spc[2] + spc[3]);
    atomicAdd(&mt->ncnt, snc[0] + snc[1] + snc[2] + snc[3]);
    pbase = atomicAdd(&mt->pcCnt, lpc < LCAP ? lpc : LCAP);
    nbase = atomicAdd(&mt->ncCnt, lnc < LCAP ? lnc : LCAP);
  }
  __syncthreads();
  const unsigned int npf = lpc < LCAP ? lpc : LCAP;
  const unsigned int nnf = lnc < LCAP ? lnc : LCAP;
  for (unsigned int i = tid; i < npf; i += 256) {
    const unsigned int gi = pbase + i;
    if (gi < CAND_CAP) pcand[gi] = lp[i];
  }
  for (unsigned int i = tid; i < nnf; i += 256) {
    const unsigned int gi = nbase + i;
    if (gi < CAND_CAP) ncand[gi] = ln[i];
  }
}

// ---- 5) exact select on candidates + finalize (bounded parallel pick) ----
#define SF_T 1024
__global__ __launch_bounds__(SF_T) void select_finalize(Meta* __restrict__ m,
                                                        const float* __restrict__ pcand,
                                                        const float* __restrict__ ncand,
                                                        float* __restrict__ out) {
  __shared__ unsigned int h[1024], P[1024];
  __shared__ unsigned int s_lo, s_hi, s_r;
  __shared__ unsigned int rmin[16], rmax[16], rcnt[16];
  __shared__ double racc[16];
  const int tid = threadIdx.x;
  const int lane = tid & 63, wid = tid >> 6;

  for (int side = 0; side < 2; ++side) {
    const unsigned int rawCnt = side ? m->ncCnt : m->pcCnt;
    const unsigned int cnt = rawCnt < CAND_CAP ? rawCnt : CAND_CAP;
    const float* cand = side ? ncand : pcand;
    if (tid == 0) s_r = side ? m->rwn : m->rwp;

    // key min/max over candidates
    unsigned int kmin = 0xFFFFFFFFu, kmax = 0u;
    for (unsigned int i = tid; i < cnt; i += SF_T) {
      const unsigned int k = f2key(cand[i]);
      kmin = min(kmin, k); kmax = max(kmax, k);
    }
#pragma unroll
    for (int o = 32; o > 0; o >>= 1) {
      kmin = min(kmin, (unsigned int)__shfl_xor((int)kmin, o));
      kmax = max(kmax, (unsigned int)__shfl_xor((int)kmax, o));
    }
    if (lane == 0) { rmin[wid] = kmin; rmax[wid] = kmax; }
    __syncthreads();
    if (tid == 0) {
      unsigned int lo = 0xFFFFFFFFu, hi = 0u;
      for (int i = 0; i < SF_T / 64; ++i) { lo = min(lo, rmin[i]); hi = max(hi, rmax[i]); }
      if (hi < lo) { lo = 0u; hi = 0u; }  // cnt==0 edge: degenerate range
      s_lo = lo; s_hi = hi + 1u;
    }

    // narrow [lo,hi) by 1024-way histogram. Bounded: span shrinks >=1024x
    // per round (4 rounds max for 2^32); 8 is a hard safety bound.
    for (int round = 0; round < 8; ++round) {
      __syncthreads();
      const unsigned int lo = s_lo, hi = s_hi;
      const unsigned int r = s_r;
      if (hi - lo <= 1u) break;
      const unsigned int span = hi - lo;
      unsigned int shift = 0;
      while (((span - 1u) >> shift) > 1023u) shift++;
      h[tid] = 0;
      __syncthreads();
      for (unsigned int i = tid; i < cnt; i += SF_T) {
        const unsigned int k = f2key(cand[i]);
        if (k >= lo && k < hi) atomicAdd(&h[(k - lo) >> shift], 1u);
      }
      __syncthreads();
      // parallel inclusive prefix over h -> P (Hillis-Steele, 10 steps)
      const unsigned int myh = h[tid];
      P[tid] = myh;
      __syncthreads();
#pragma unroll
      for (int off = 1; off < 1024; off <<= 1) {
        const unsigned int t = (tid >= off) ? P[tid - off] : 0u;
        __syncthreads();
        P[tid] += t;
        __syncthreads();
      }
      const unsigned int total = P[SF_T - 1];
      if (total == 0u) {               // no keys in range: collapse & exit
        if (tid == 0) s_hi = s_lo + 1u;
        continue;                       // next round breaks
      }
      const unsigned int rr = r < total ? r : total - 1u;  // owner guaranteed
      const unsigned int incl = P[tid];
      const unsigned int excl = incl - myh;
      if (excl <= rr && rr < incl) {   // exactly one owner (myh>0 there)
        s_r = rr - excl;
        const unsigned int nlo = lo + ((unsigned int)tid << shift);
        unsigned int nhi = nlo + (1u << shift);
        if (nhi > hi || nhi < nlo) nhi = hi;
        s_lo = nlo; s_hi = nhi;
      }
    }
    __syncthreads();
    const float T = key2f(s_lo);

    // strict boundary contributions
    float accf = 0.f;
    unsigned int c2 = 0;
    for (unsigned int i = tid; i < cnt; i += SF_T) {
      const float s = cand[i];
      if (side == 0) { if (s > T) { c2++; accf += fmaxf(1.0f - s, 0.0f); } }
      else           { if (s < T) { c2++; accf += fmaxf(s, 0.0f); } }
    }
    double accd = accf;
#pragma unroll
    for (int o = 32; o > 0; o >>= 1) { accd += __shfl_xor(accd, o); c2 += __shfl_xor(c2, o); }
    if (lane == 0) { racc[wid] = accd; rcnt[wid] = c2; }
    __syncthreads();
    if (tid == 0) {
      double a = 0.0;
      unsigned int c = 0;
      for (int i = 0; i < SF_T / 64; ++i) { a += racc[i]; c += rcnt[i]; }
      if (side == 0) { m->psum += a; m->pcnt += c; }
      else           { m->nsum += a; m->ncnt += c; }
    }
    __syncthreads();
  }
  if (tid == 0)
    out[0] = (float)(m->psum / (double)m->pcnt + m->nsum / (double)m->ncnt);
}

extern "C" void kernel_launch(void* const* d_in, const int* in_sizes, int n_in,
                              void* d_out, int out_size, void* d_ws, size_t ws_size,
                              hipStream_t stream) {
  const float* x = (const float*)d_in[0];
  float* out = (float*)d_out;
  char* ws = (char*)d_ws;

  unsigned short* xnb = (unsigned short*)ws;                      // 4 MB
  float* pcand = (float*)(ws + (size_t)N * D * 2);                // 1 MB
  float* ncand = (float*)(ws + (size_t)N * D * 2 + CAND_CAP * 4); // 1 MB
  Meta* meta = (Meta*)(ws + (size_t)N * D * 2 + 2ull * CAND_CAP * 4);

  const unsigned int kneg = (unsigned int)ceil((double)NN * 0.2);          // 3355444
  const unsigned int kpos = (unsigned int)ceil((double)NN * (1.0 - 0.2));  // 13421773

  hipMemsetAsync(meta, 0, sizeof(Meta), stream);
  norm_conv<<<N, 256, 0, stream>>>(x, xnb);
  dim3 ggrid(N / BM, N / BM);  // upper-triangle blocks compute; lower exit
  gemm_hist<<<ggrid, 256, 0, stream>>>(xnb, meta);
  scan_bins<<<1, 256, 0, stream>>>(meta, kneg, kpos);
  gemm_loss<<<ggrid, 256, 0, stream>>>(xnb, meta, pcand, ncand);
  select_finalize<<<1, SF_T, 0, stream>>>(meta, pcand, ncand, out);
}

// Round 9
// 153.138 us; speedup vs baseline: 1.7251x; 1.7251x over previous
//
#include <hip/hip_runtime.h>
#include <hip/hip_bf16.h>
#include <math.h>

// AdaptiveContrastiveLoss: x[4096][512] f32 -> scalar f32.
// R8: select_finalize was 150us — single block scanning 104K candidates at
// MLP=1 + 46 block-wide barriers. Added multi-block fine-refinement
// (4096 sub-bins within the coarse bin) so select_finalize sees ~25-60
// candidates instead of 104K. gemm passes unchanged from R7.
// ws: xnb 4MB | pcand 1MB | ncand 1MB | pc2 64KB | nc2 64KB | Meta ~41KB.

#define N 4096
#define D 512
#define NN 16777216u
#define NB 2048          // coarse uniform value bins
#define FNB 4096         // fine sub-bins within one coarse bin
#define CAND_CAP 262144  // per-side coarse candidate capacity (1MB)
#define LCAP 512         // gemm_loss per-block LDS candidate capacity
#define C2CAP 16384      // per-side fine candidate capacity
#define LC2 256          // cand_compact per-block LDS capacity

typedef __attribute__((ext_vector_type(8))) short bf16x8;
typedef __attribute__((ext_vector_type(4))) float f32x4;

struct Meta {
  unsigned int hist[NB];        // coarse histogram
  unsigned int fhist[2][FNB];   // fine histograms (0=pos, 1=neg)
  unsigned int bp, rwp;         // pos coarse bin + rank within (then fine rank)
  unsigned int bn_, rwn;        // neg coarse bin + rank within (then fine rank)
  unsigned int fbp, fbn;        // fine sub-bin selections
  unsigned int pcCnt, ncCnt;    // coarse candidate counts
  unsigned int c2p, c2n;        // fine candidate counts
  unsigned int pcnt, ncnt;      // strict mask counts
  double psum, nsum;            // strict mask numerators
};

// coarse value->bin: floor((s+1)*1024), clamped. identical math everywhere.
__device__ __forceinline__ int val2bin(float s) {
  int b = (int)fmaf(s, 1024.0f, 1024.0f);
  return b < 0 ? 0 : (b > NB - 1 ? NB - 1 : b);
}
// fine sub-bin within coarse bin b: monotone nondecreasing in s.
// t = fmaf(s,1024,1024) in [b,b+1) for interior bins; t-(float)b is exact
// (Sterbenz); clamp handles edge/clamped-bin cases (stays monotone).
__device__ __forceinline__ unsigned int finebin(float s, unsigned int b) {
  const float t = fmaf(s, 1024.0f, 1024.0f);
  const int fb = (int)((t - (float)b) * (float)FNB);
  return (unsigned int)(fb < 0 ? 0 : (fb > FNB - 1 ? FNB - 1 : fb));
}
__device__ __forceinline__ unsigned int f2key(float f) {
  unsigned int u = __float_as_uint(f);
  return (u & 0x80000000u) ? ~u : (u | 0x80000000u);
}
__device__ __forceinline__ float key2f(unsigned int k) {
  unsigned int u = (k & 0x80000000u) ? (k ^ 0x80000000u) : ~k;
  return __uint_as_float(u);
}
__device__ __forceinline__ unsigned short f2bf(float f) {  // RNE
  unsigned int u = __float_as_uint(f);
  u += 0x7FFFu + ((u >> 16) & 1u);
  return (unsigned short)(u >> 16);
}

// ---- 1) row norms + normalize + f32->bf16 convert ----
__global__ __launch_bounds__(256) void norm_conv(const float* __restrict__ x,
                                                 unsigned short* __restrict__ xnb) {
  const int row = blockIdx.x;
  const int tid = threadIdx.x;
  const float2 v = ((const float2*)(x + (size_t)row * D))[tid];
  float s = v.x * v.x + v.y * v.y;
#pragma unroll
  for (int o = 32; o > 0; o >>= 1) s += __shfl_xor(s, o);
  __shared__ float wsum[4];
  __shared__ float s_rinv;
  if ((tid & 63) == 0) wsum[tid >> 6] = s;
  __syncthreads();
  if (tid == 0) {
    float t = wsum[0] + wsum[1] + wsum[2] + wsum[3];
    s_rinv = 1.0f / fmaxf(sqrtf(t), 1e-8f);
  }
  __syncthreads();
  const float r = s_rinv;
  ((ushort2*)(xnb + (size_t)row * D))[tid] = make_ushort2(f2bf(v.x * r), f2bf(v.y * r));
}

// ---- shared GEMM tile core: 128x128 tile, 4 waves, acc[4][4] f32x4/lane ----
#define BM 128
#define BK 64
#define LDK 72  // padded row stride (144B: 16B-aligned, 2-way-bank free)
__device__ __forceinline__ void compute_tile(const unsigned short* __restrict__ xnb,
                                             unsigned short As[BM][LDK],
                                             unsigned short Bs[BM][LDK],
                                             int bm, int bn, int tid,
                                             f32x4 acc[4][4]) {
  const int w = tid >> 6, l = tid & 63;
  const int wr = w >> 1, wc = w & 1;
  const int lr = l & 15, lk = (l >> 4) * 8;
  const int srow = tid >> 3;        // 0..31
  const int skoff = (tid & 7) * 8;  // 0..56

  for (int kt = 0; kt < D; kt += BK) {
    bf16x8 av[4], bv[4];
#pragma unroll
    for (int r4 = 0; r4 < 4; ++r4) {
      const int row = srow + r4 * 32;
      av[r4] = *(const bf16x8*)&xnb[(size_t)(bm + row) * D + kt + skoff];
      bv[r4] = *(const bf16x8*)&xnb[(size_t)(bn + row) * D + kt + skoff];
    }
    __syncthreads();
#pragma unroll
    for (int r4 = 0; r4 < 4; ++r4) {
      const int row = srow + r4 * 32;
      *(bf16x8*)&As[row][skoff] = av[r4];
      *(bf16x8*)&Bs[row][skoff] = bv[r4];
    }
    __syncthreads();
#pragma unroll
    for (int kk = 0; kk < BK; kk += 32) {
      bf16x8 af[4], bf[4];
#pragma unroll
      for (int m = 0; m < 4; ++m)
        af[m] = *(const bf16x8*)&As[wr * 64 + m * 16 + lr][kk + lk];
#pragma unroll
      for (int n = 0; n < 4; ++n)
        bf[n] = *(const bf16x8*)&Bs[wc * 64 + n * 16 + lr][kk + lk];
#pragma unroll
      for (int m = 0; m < 4; ++m)
#pragma unroll
        for (int n = 0; n < 4; ++n)
          acc[m][n] = __builtin_amdgcn_mfma_f32_16x16x32_bf16(af[m], bf[n], acc[m][n], 0, 0, 0);
    }
  }
}

// ---- 2) GEMM pass A (upper triangle only): weighted tile histogram ----
__global__ __launch_bounds__(256) void gemm_hist(const unsigned short* __restrict__ xnb,
                                                 Meta* __restrict__ mt) {
  if (blockIdx.x > blockIdx.y) return;  // lower-triangle tiles: mirrors of upper
  __shared__ unsigned short As[BM][LDK];
  __shared__ unsigned short Bs[BM][LDK];
  __shared__ unsigned int h[NB];
  const int tid = threadIdx.x;
  const unsigned int wgt = (blockIdx.x == blockIdx.y) ? 1u : 2u;
  for (int i = tid; i < NB; i += 256) h[i] = 0;

  f32x4 acc[4][4] = {};
  compute_tile(xnb, As, Bs, blockIdx.x * BM, blockIdx.y * BM, tid, acc);

  __syncthreads();
#pragma unroll
  for (int m = 0; m < 4; ++m)
#pragma unroll
    for (int n = 0; n < 4; ++n)
#pragma unroll
      for (int e = 0; e < 4; ++e)
        atomicAdd(&h[val2bin(acc[m][n][e])], wgt);
  __syncthreads();
  for (int i = tid; i < NB; i += 256) {
    const unsigned int c = h[i];
    if (c) atomicAdd(&mt->hist[i], c);
  }
}

// ---- 3) coarse threshold bins + ranks: parallel prefix, owner resolve ----
__global__ __launch_bounds__(256) void scan_bins(Meta* __restrict__ m,
                                                 unsigned int kneg, unsigned int kpos) {
  __shared__ unsigned int part[256], Q[256];
  __shared__ unsigned int res_b[2], res_r[2];
  const int tid = threadIdx.x;
  if (tid < 2) { res_b[tid] = NB - 1; res_r[tid] = 0; }  // safe defaults
  const unsigned int base = tid * (NB / 256);
  unsigned int loc[NB / 256];
  unsigned int s = 0;
#pragma unroll
  for (int i = 0; i < NB / 256; ++i) { loc[i] = m->hist[base + i]; s += loc[i]; }
  part[tid] = s;
  Q[tid] = s;
  __syncthreads();
#pragma unroll
  for (int off = 1; off < 256; off <<= 1) {
    unsigned int t = (tid >= off) ? Q[tid - off] : 0u;
    __syncthreads();
    Q[tid] += t;
    __syncthreads();
  }
  const unsigned int total = Q[255];
  const unsigned int incl = Q[tid];
  const unsigned int excl = incl - part[tid];
  const unsigned int targets[2] = {kpos, kneg};
#pragma unroll
  for (int t = 0; t < 2; ++t) {
    const unsigned int r = (total == 0u) ? 0u
                         : (targets[t] < total ? targets[t] : total - 1u);
    if (total != 0u && excl <= r && r < incl) {  // exactly one owner thread
      unsigned int rr = r - excl, cum = 0;
      int bsel = -1;
#pragma unroll
      for (int i = 0; i < NB / 256; ++i) {
        if (bsel < 0 && cum + loc[i] > rr) bsel = i;
        else if (bsel < 0) cum += loc[i];
      }
      if (bsel < 0) bsel = NB / 256 - 1;
      res_b[t] = base + (unsigned int)bsel;
      res_r[t] = rr - cum;
    }
  }
  __syncthreads();
  if (tid == 0) {
    m->bp = res_b[0]; m->rwp = res_r[0];
    m->bn_ = res_b[1]; m->rwn = res_r[1];
  }
}

// ---- 4) GEMM pass B (upper triangle only): weighted strict loss +
//         coarse boundary-bin candidate compaction ----
__global__ __launch_bounds__(256) void gemm_loss(const unsigned short* __restrict__ xnb,
                                                 Meta* __restrict__ mt,
                                                 float* __restrict__ pcand,
                                                 float* __restrict__ ncand) {
  if (blockIdx.x > blockIdx.y) return;
  __shared__ unsigned short As[BM][LDK];
  __shared__ unsigned short Bs[BM][LDK];
  __shared__ float lp[LCAP], ln[LCAP];
  __shared__ unsigned int lpc, lnc, pbase, nbase;
  const int tid = threadIdx.x;
  const unsigned int wgt = (blockIdx.x == blockIdx.y) ? 1u : 2u;
  if (tid == 0) { lpc = 0; lnc = 0; }

  f32x4 acc[4][4] = {};
  compute_tile(xnb, As, Bs, blockIdx.x * BM, blockIdx.y * BM, tid, acc);

  const unsigned int bp = mt->bp, bn = mt->bn_;
  float ps = 0.f, ns = 0.f;
  unsigned int pc = 0, nc = 0;
  const float fw = (float)wgt;
#pragma unroll
  for (int m = 0; m < 4; ++m)
#pragma unroll
    for (int n = 0; n < 4; ++n)
#pragma unroll
      for (int e = 0; e < 4; ++e) {
        const float s = acc[m][n][e];
        const unsigned int b = (unsigned int)val2bin(s);
        if (b > bp) { pc += wgt; ps += fw * fmaxf(1.0f - s, 0.0f); }
        else if (b == bp) {
          const unsigned int i = atomicAdd(&lpc, wgt);
          if (i < LCAP) lp[i] = s;
          if (wgt == 2u && i + 1u < LCAP) lp[i + 1u] = s;
        }
        if (b < bn) { nc += wgt; ns += fw * fmaxf(s, 0.0f); }
        else if (b == bn) {
          const unsigned int i = atomicAdd(&lnc, wgt);
          if (i < LCAP) ln[i] = s;
          if (wgt == 2u && i + 1u < LCAP) ln[i + 1u] = s;
        }
      }
  double psd = ps, nsd = ns;
#pragma unroll
  for (int o = 32; o > 0; o >>= 1) {
    psd += __shfl_xor(psd, o);
    nsd += __shfl_xor(nsd, o);
    pc += __shfl_xor(pc, o);
    nc += __shfl_xor(nc, o);
  }
  __shared__ double sps[4], sns[4];
  __shared__ unsigned int spc[4], snc[4];
  if ((tid & 63) == 0) { const int w = tid >> 6; sps[w] = psd; sns[w] = nsd; spc[w] = pc; snc[w] = nc; }
  __syncthreads();
  if (tid == 0) {
    atomicAdd(&mt->psum, sps[0] + sps[1] + sps[2] + sps[3]);
    atomicAdd(&mt->nsum, sns[0] + sns[1] + sns[2] + sns[3]);
    atomicAdd(&mt->pcnt, spc[0] + spc[1] + spc[2] + spc[3]);
    atomicAdd(&mt->ncnt, snc[0] + snc[1] + snc[2] + snc[3]);
    pbase = atomicAdd(&mt->pcCnt, lpc < LCAP ? lpc : LCAP);
    nbase = atomicAdd(&mt->ncCnt, lnc < LCAP ? lnc : LCAP);
  }
  __syncthreads();
  const unsigned int npf = lpc < LCAP ? lpc : LCAP;
  const unsigned int nnf = lnc < LCAP ? lnc : LCAP;
  for (unsigned int i = tid; i < npf; i += 256) {
    const unsigned int gi = pbase + i;
    if (gi < CAND_CAP) pcand[gi] = lp[i];
  }
  for (unsigned int i = tid; i < nnf; i += 256) {
    const unsigned int gi = nbase + i;
    if (gi < CAND_CAP) ncand[gi] = ln[i];
  }
}

// ---- 5) fine histogram over coarse candidates (multi-block) ----
__global__ __launch_bounds__(256) void cand_fhist(const float* __restrict__ pcand,
                                                  const float* __restrict__ ncand,
                                                  Meta* __restrict__ m) {
  __shared__ unsigned int h[2][FNB];
  const int tid = threadIdx.x;
  for (int i = tid; i < 2 * FNB; i += 256) ((unsigned int*)h)[i] = 0;
  __syncthreads();
  const unsigned int pcn = min(m->pcCnt, (unsigned int)CAND_CAP);
  const unsigned int ncn = min(m->ncCnt, (unsigned int)CAND_CAP);
  const unsigned int cbp = m->bp, cbn = m->bn_;
  const unsigned int stride = gridDim.x * 256u;
  for (unsigned int i = blockIdx.x * 256u + tid; i < pcn; i += stride)
    atomicAdd(&h[0][finebin(pcand[i], cbp)], 1u);
  for (unsigned int i = blockIdx.x * 256u + tid; i < ncn; i += stride)
    atomicAdd(&h[1][finebin(ncand[i], cbn)], 1u);
  __syncthreads();
  for (int i = tid; i < FNB; i += 256) {
    if (h[0][i]) atomicAdd(&m->fhist[0][i], h[0][i]);
    if (h[1][i]) atomicAdd(&m->fhist[1][i], h[1][i]);
  }
}

// ---- 6) pick fine sub-bin + refined rank (parallel prefix, both sides) ----
__global__ __launch_bounds__(256) void cand_pick(Meta* __restrict__ m) {
  __shared__ unsigned int part[256], Q[256];
  __shared__ unsigned int res_b, res_r;
  const int tid = threadIdx.x;
  for (int side = 0; side < 2; ++side) {
    const unsigned int* fh = m->fhist[side];
    const unsigned int target = side ? m->rwn : m->rwp;
    if (tid == 0) { res_b = FNB - 1; res_r = 0; }
    const unsigned int base = tid * (FNB / 256);
    unsigned int loc[FNB / 256];
    unsigned int s = 0;
#pragma unroll
    for (int i = 0; i < FNB / 256; ++i) { loc[i] = fh[base + i]; s += loc[i]; }
    part[tid] = s;
    Q[tid] = s;
    __syncthreads();
#pragma unroll
    for (int off = 1; off < 256; off <<= 1) {
      unsigned int t = (tid >= off) ? Q[tid - off] : 0u;
      __syncthreads();
      Q[tid] += t;
      __syncthreads();
    }
    const unsigned int total = Q[255];
    const unsigned int incl = Q[tid];
    const unsigned int excl = incl - part[tid];
    const unsigned int r = (total == 0u) ? 0u : (target < total ? target : total - 1u);
    if (total != 0u && excl <= r && r < incl) {  // exactly one owner
      unsigned int rr = r - excl, cum = 0;
      int bsel = -1;
#pragma unroll
      for (int i = 0; i < FNB / 256; ++i) {
        if (bsel < 0 && cum + loc[i] > rr) bsel = i;
        else if (bsel < 0) cum += loc[i];
      }
      if (bsel < 0) bsel = FNB / 256 - 1;
      res_b = base + (unsigned int)bsel;
      res_r = rr - cum;
    }
    __syncthreads();
    if (tid == 0) {
      if (side == 0) { m->fbp = res_b; m->rwp = res_r; }
      else           { m->fbn = res_b; m->rwn = res_r; }
    }
    __syncthreads();
  }
}

// ---- 7) strict sums for fb != fbsel + compact fb == fbsel (multi-block) ----
// monotone finebin: fb > fbp  =>  v strictly > threshold (threshold in fbp).
__global__ __launch_bounds__(256) void cand_compact(const float* __restrict__ pcand,
                                                    const float* __restrict__ ncand,
                                                    Meta* __restrict__ m,
                                                    float* __restrict__ pc2,
                                                    float* __restrict__ nc2) {
  __shared__ float bp2[LC2], bn2[LC2];
  __shared__ unsigned int cp, cn, basep, basen;
  const int tid = threadIdx.x;
  if (tid == 0) { cp = 0; cn = 0; }
  __syncthreads();
  const unsigned int pcn = min(m->pcCnt, (unsigned int)CAND_CAP);
  const unsigned int ncn = min(m->ncCnt, (unsigned int)CAND_CAP);
  const unsigned int cbp = m->bp, cbn = m->bn_;
  const unsigned int fbp = m->fbp, fbn = m->fbn;
  float ps = 0.f, ns = 0.f;
  unsigned int pc = 0, nc = 0;
  const unsigned int stride = gridDim.x * 256u;
  for (unsigned int i = blockIdx.x * 256u + tid; i < pcn; i += stride) {
    const float s = pcand[i];
    const unsigned int fb = finebin(s, cbp);
    if (fb > fbp) { pc++; ps += fmaxf(1.0f - s, 0.0f); }
    else if (fb == fbp) { const unsigned int j = atomicAdd(&cp, 1u); if (j < LC2) bp2[j] = s; }
  }
  for (unsigned int i = blockIdx.x * 256u + tid; i < ncn; i += stride) {
    const float s = ncand[i];
    const unsigned int fb = finebin(s, cbn);
    if (fb < fbn) { nc++; ns += fmaxf(s, 0.0f); }
    else if (fb == fbn) { const unsigned int j = atomicAdd(&cn, 1u); if (j < LC2) bn2[j] = s; }
  }
  double psd = ps, nsd = ns;
#pragma unroll
  for (int o = 32; o > 0; o >>= 1) {
    psd += __shfl_xor(psd, o);
    nsd += __shfl_xor(nsd, o);
    pc += __shfl_xor(pc, o);
    nc += __shfl_xor(nc, o);
  }
  __shared__ double sps[4], sns[4];
  __shared__ unsigned int spc[4], snc[4];
  if ((tid & 63) == 0) { const int w = tid >> 6; sps[w] = psd; sns[w] = nsd; spc[w] = pc; snc[w] = nc; }
  __syncthreads();
  if (tid == 0) {
    const double a = sps[0] + sps[1] + sps[2] + sps[3];
    const double b = sns[0] + sns[1] + sns[2] + sns[3];
    const unsigned int c = spc[0] + spc[1] + spc[2] + spc[3];
    const unsigned int d2 = snc[0] + snc[1] + snc[2] + snc[3];
    if (a != 0.0) atomicAdd(&m->psum, a);
    if (b != 0.0) atomicAdd(&m->nsum, b);
    if (c) atomicAdd(&m->pcnt, c);
    if (d2) atomicAdd(&m->ncnt, d2);
    basep = atomicAdd(&m->c2p, cp < LC2 ? cp : LC2);
    basen = atomicAdd(&m->c2n, cn < LC2 ? cn : LC2);
  }
  __syncthreads();
  const unsigned int npf = cp < LC2 ? cp : LC2;
  const unsigned int nnf = cn < LC2 ? cn : LC2;
  for (unsigned int i = tid; i < npf; i += 256) {
    const unsigned int gi = basep + i;
    if (gi < C2CAP) pc2[gi] = bp2[i];
  }
  for (unsigned int i = tid; i < nnf; i += 256) {
    const unsigned int gi = basen + i;
    if (gi < C2CAP) nc2[gi] = bn2[i];
  }
}

// ---- 8) exact select on ~25-60 fine candidates + finalize ----
#define SF_T 1024
__global__ __launch_bounds__(SF_T) void select_finalize(Meta* __restrict__ m,
                                                        const float* __restrict__ pcand,
                                                        const float* __restrict__ ncand,
                                                        float* __restrict__ out) {
  __shared__ unsigned int h[1024], P[1024];
  __shared__ unsigned int s_lo, s_hi, s_r;
  __shared__ unsigned int rmin[16], rmax[16], rcnt[16];
  __shared__ double racc[16];
  const int tid = threadIdx.x;
  const int lane = tid & 63, wid = tid >> 6;

  for (int side = 0; side < 2; ++side) {
    const unsigned int rawCnt = side ? m->c2n : m->c2p;
    const unsigned int cnt = rawCnt < C2CAP ? rawCnt : C2CAP;
    const float* cand = side ? ncand : pcand;
    if (tid == 0) s_r = side ? m->rwn : m->rwp;

    // key min/max over candidates
    unsigned int kmin = 0xFFFFFFFFu, kmax = 0u;
    for (unsigned int i = tid; i < cnt; i += SF_T) {
      const unsigned int k = f2key(cand[i]);
      kmin = min(kmin, k); kmax = max(kmax, k);
    }
#pragma unroll
    for (int o = 32; o > 0; o >>= 1) {
      kmin = min(kmin, (unsigned int)__shfl_xor((int)kmin, o));
      kmax = max(kmax, (unsigned int)__shfl_xor((int)kmax, o));
    }
    if (lane == 0) { rmin[wid] = kmin; rmax[wid] = kmax; }
    __syncthreads();
    if (tid == 0) {
      unsigned int lo = 0xFFFFFFFFu, hi = 0u;
      for (int i = 0; i < SF_T / 64; ++i) { lo = min(lo, rmin[i]); hi = max(hi, rmax[i]); }
      if (hi < lo) { lo = 0u; hi = 0u; }  // cnt==0 edge: degenerate range
      s_lo = lo; s_hi = hi + 1u;
    }

    // narrow [lo,hi): bounded (span shrinks >=1024x/round; 8 hard cap)
    for (int round = 0; round < 8; ++round) {
      __syncthreads();
      const unsigned int lo = s_lo, hi = s_hi;
      const unsigned int r = s_r;
      if (hi - lo <= 1u) break;
      const unsigned int span = hi - lo;
      unsigned int shift = 0;
      while (((span - 1u) >> shift) > 1023u) shift++;
      h[tid] = 0;
      __syncthreads();
      for (unsigned int i = tid; i < cnt; i += SF_T) {
        const unsigned int k = f2key(cand[i]);
        if (k >= lo && k < hi) atomicAdd(&h[(k - lo) >> shift], 1u);
      }
      __syncthreads();
      const unsigned int myh = h[tid];
      P[tid] = myh;
      __syncthreads();
#pragma unroll
      for (int off = 1; off < 1024; off <<= 1) {
        const unsigned int t = (tid >= off) ? P[tid - off] : 0u;
        __syncthreads();
        P[tid] += t;
        __syncthreads();
      }
      const unsigned int total = P[SF_T - 1];
      if (total == 0u) {               // no keys in range: collapse & exit
        if (tid == 0) s_hi = s_lo + 1u;
        continue;
      }
      const unsigned int rr = r < total ? r : total - 1u;  // owner guaranteed
      const unsigned int incl = P[tid];
      const unsigned int excl = incl - myh;
      if (excl <= rr && rr < incl) {   // exactly one owner (myh>0 there)
        s_r = rr - excl;
        const unsigned int nlo = lo + ((unsigned int)tid << shift);
        unsigned int nhi = nlo + (1u << shift);
        if (nhi > hi || nhi < nlo) nhi = hi;
        s_lo = nlo; s_hi = nhi;
      }
    }
    __syncthreads();
    const float T = key2f(s_lo);

    // strict boundary contributions among fine candidates
    float accf = 0.f;
    unsigned int c2 = 0;
    for (unsigned int i = tid; i < cnt; i += SF_T) {
      const float s = cand[i];
      if (side == 0) { if (s > T) { c2++; accf += fmaxf(1.0f - s, 0.0f); } }
      else           { if (s < T) { c2++; accf += fmaxf(s, 0.0f); } }
    }
    double accd = accf;
#pragma unroll
    for (int o = 32; o > 0; o >>= 1) { accd += __shfl_xor(accd, o); c2 += __shfl_xor(c2, o); }
    if (lane == 0) { racc[wid] = accd; rcnt[wid] = c2; }
    __syncthreads();
    if (tid == 0) {
      double a = 0.0;
      unsigned int c = 0;
      for (int i = 0; i < SF_T / 64; ++i) { a += racc[i]; c += rcnt[i]; }
      if (side == 0) { m->psum += a; m->pcnt += c; }
      else           { m->nsum += a; m->ncnt += c; }
    }
    __syncthreads();
  }
  if (tid == 0)
    out[0] = (float)(m->psum / (double)m->pcnt + m->nsum / (double)m->ncnt);
}

extern "C" void kernel_launch(void* const* d_in, const int* in_sizes, int n_in,
                              void* d_out, int out_size, void* d_ws, size_t ws_size,
                              hipStream_t stream) {
  const float* x = (const float*)d_in[0];
  float* out = (float*)d_out;
  char* ws = (char*)d_ws;

  unsigned short* xnb = (unsigned short*)ws;                                   // 4 MB
  float* pcand = (float*)(ws + (size_t)N * D * 2);                             // 1 MB
  float* ncand = (float*)(ws + (size_t)N * D * 2 + (size_t)CAND_CAP * 4);      // 1 MB
  float* pc2 = (float*)(ws + (size_t)N * D * 2 + 2ull * CAND_CAP * 4);         // 64 KB
  float* nc2 = (float*)(ws + (size_t)N * D * 2 + 2ull * CAND_CAP * 4 + (size_t)C2CAP * 4);
  Meta* meta = (Meta*)(ws + (size_t)N * D * 2 + 2ull * CAND_CAP * 4 + 2ull * C2CAP * 4);

  const unsigned int kneg = (unsigned int)ceil((double)NN * 0.2);          // 3355444
  const unsigned int kpos = (unsigned int)ceil((double)NN * (1.0 - 0.2));  // 13421773

  hipMemsetAsync(meta, 0, sizeof(Meta), stream);
  norm_conv<<<N, 256, 0, stream>>>(x, xnb);
  dim3 ggrid(N / BM, N / BM);  // upper-triangle blocks compute; lower exit
  gemm_hist<<<ggrid, 256, 0, stream>>>(xnb, meta);
  scan_bins<<<1, 256, 0, stream>>>(meta, kneg, kpos);
  gemm_loss<<<ggrid, 256, 0, stream>>>(xnb, meta, pcand, ncand);
  cand_fhist<<<128, 256, 0, stream>>>(pcand, ncand, meta);
  cand_pick<<<1, 256, 0, stream>>>(meta);
  cand_compact<<<128, 256, 0, stream>>>(pcand, ncand, meta, pc2, nc2);
  select_finalize<<<1, SF_T, 0, stream>>>(meta, pc2, nc2, out);
}

// Round 10
// 138.944 us; speedup vs baseline: 1.9013x; 1.1022x over previous
//
#include <hip/hip_runtime.h>
#include <hip/hip_bf16.h>
#include <math.h>

// AdaptiveContrastiveLoss: x[4096][512] f32 -> scalar f32.
// R9: single fused GEMM pass. Per-bin sufficient statistics (count, sum-s,
// exact top-bin pos term) make the second GEMM pass unnecessary; threshold
// is taken at the containing-bin edge (error bound ~8e-4 << 1.875e-2 tol;
// neg side exactly 0 both ways since neg threshold < 0). 8-wave blocks
// (512 thr) double latency hiding. Deterministic slice-store + tree reduce.
// ws: xnb 4MB | slice_cnt 4.3MB | slice_ssum 4.3MB | slice_top 2KB |
//     cnt_part 32KB | ssum_part 64KB.

#define N 4096
#define D 512
#define NN 16777216u
#define NBF 2048         // uniform value bins
#define NSLICE 528       // upper-triangle 128x128 tiles of a 4096^2 matrix

typedef __attribute__((ext_vector_type(8))) short bf16x8;
typedef __attribute__((ext_vector_type(4))) float f32x4;

// monotone value->bin: floor((s+1)*1024), clamped to [0, NBF-1].
// bin edge at s==0 is exact (t=1024.0), so bins >= 1024 <=> s >= 0.
__device__ __forceinline__ int val2bin(float s) {
  int b = (int)fmaf(s, 1024.0f, 1024.0f);
  return b < 0 ? 0 : (b > NBF - 1 ? NBF - 1 : b);
}
__device__ __forceinline__ unsigned short f2bf(float f) {  // RNE
  unsigned int u = __float_as_uint(f);
  u += 0x7FFFu + ((u >> 16) & 1u);
  return (unsigned short)(u >> 16);
}

// ---- 1) row norms + normalize + f32->bf16 convert ----
__global__ __launch_bounds__(256) void norm_conv(const float* __restrict__ x,
                                                 unsigned short* __restrict__ xnb) {
  const int row = blockIdx.x;
  const int tid = threadIdx.x;
  const float2 v = ((const float2*)(x + (size_t)row * D))[tid];
  float s = v.x * v.x + v.y * v.y;
#pragma unroll
  for (int o = 32; o > 0; o >>= 1) s += __shfl_xor(s, o);
  __shared__ float wsum[4];
  __shared__ float s_rinv;
  if ((tid & 63) == 0) wsum[tid >> 6] = s;
  __syncthreads();
  if (tid == 0) {
    float t = wsum[0] + wsum[1] + wsum[2] + wsum[3];
    s_rinv = 1.0f / fmaxf(sqrtf(t), 1e-8f);
  }
  __syncthreads();
  const float r = s_rinv;
  ((ushort2*)(xnb + (size_t)row * D))[tid] = make_ushort2(f2bf(v.x * r), f2bf(v.y * r));
}

// ---- 2) fused GEMM + per-bin stats (upper-triangle tiles, weighted) ----
// 128x128 tile, 8 waves (4M x 2N), each wave 32x64 -> acc[2][4] 16x16x32.
#define BM 128
#define BK 64
#define LDK 72  // padded row stride (144B: 16B-aligned, 2-way-bank free)
__global__ __launch_bounds__(512, 4) void gemm_fused(const unsigned short* __restrict__ xnb,
                                                     unsigned int* __restrict__ slice_cnt,
                                                     float* __restrict__ slice_ssum,
                                                     float* __restrict__ slice_top) {
  const int bx = blockIdx.x, by = blockIdx.y;
  if (bx > by) return;  // lower-triangle tiles are bitwise mirrors of upper
  __shared__ unsigned short As[BM][LDK];
  __shared__ unsigned short Bs[BM][LDK];
  __shared__ unsigned int cnt[NBF];
  __shared__ float ssm[NBF];
  __shared__ float stop;  // exact sum of fmax(1-s,0) for top bin (s>=1 possible)
  const int tid = threadIdx.x;
  for (int i = tid; i < NBF; i += 512) { cnt[i] = 0u; ssm[i] = 0.f; }
  if (tid == 0) stop = 0.f;

  const int w = tid >> 6, l = tid & 63;
  const int wr = w >> 1, wc = w & 1;       // wave grid 4 x 2
  const int lr = l & 15, lk = (l >> 4) * 8;
  const int srow = tid >> 3;               // 0..63
  const int skoff = (tid & 7) * 8;         // 0..56
  const int bm = bx * BM, bn = by * BM;

  f32x4 acc[2][4] = {};

#pragma unroll
  for (int kt = 0; kt < D; kt += BK) {
    bf16x8 av[2], bv[2];
#pragma unroll
    for (int p = 0; p < 2; ++p) {
      av[p] = *(const bf16x8*)&xnb[(size_t)(bm + srow + p * 64) * D + kt + skoff];
      bv[p] = *(const bf16x8*)&xnb[(size_t)(bn + srow + p * 64) * D + kt + skoff];
    }
    __syncthreads();  // previous iter's LDS reads done (and bin-array init on iter 0)
#pragma unroll
    for (int p = 0; p < 2; ++p) {
      *(bf16x8*)&As[srow + p * 64][skoff] = av[p];
      *(bf16x8*)&Bs[srow + p * 64][skoff] = bv[p];
    }
    __syncthreads();
#pragma unroll
    for (int kk = 0; kk < BK; kk += 32) {
      bf16x8 af[2], bf4[4];
#pragma unroll
      for (int m = 0; m < 2; ++m)
        af[m] = *(const bf16x8*)&As[wr * 32 + m * 16 + lr][kk + lk];
#pragma unroll
      for (int n = 0; n < 4; ++n)
        bf4[n] = *(const bf16x8*)&Bs[wc * 64 + n * 16 + lr][kk + lk];
#pragma unroll
      for (int m = 0; m < 2; ++m)
#pragma unroll
        for (int n = 0; n < 4; ++n)
          acc[m][n] = __builtin_amdgcn_mfma_f32_16x16x32_bf16(af[m], bf4[n], acc[m][n], 0, 0, 0);
    }
  }

  // epilogue: bin stats (positions irrelevant — only the value multiset matters)
  const unsigned int wg = (bx == by) ? 1u : 2u;
  const float fw = (float)wg;
  __syncthreads();
#pragma unroll
  for (int m = 0; m < 2; ++m)
#pragma unroll
    for (int n = 0; n < 4; ++n)
#pragma unroll
      for (int e = 0; e < 4; ++e) {
        const float s = acc[m][n][e];
        const int b = val2bin(s);
        atomicAdd(&cnt[b], wg);
        atomicAdd(&ssm[b], fw * s);
        if (b == NBF - 1) atomicAdd(&stop, fw * fmaxf(1.0f - s, 0.0f));
      }
  __syncthreads();
  // deterministic flush: plain stores to this block's private slice
  const int slice = by * (by + 1) / 2 + bx;
  unsigned int* oc = slice_cnt + (size_t)slice * NBF;
  float* os = slice_ssum + (size_t)slice * NBF;
  for (int i = tid; i < NBF; i += 512) { oc[i] = cnt[i]; os[i] = ssm[i]; }
  if (tid == 0) slice_top[slice] = stop;
}

// ---- 3) tree-reduce slices: 8192 threads, thread = (chunk c, bin b) ----
__global__ __launch_bounds__(256) void reduce_bins(const unsigned int* __restrict__ slice_cnt,
                                                   const float* __restrict__ slice_ssum,
                                                   unsigned int* __restrict__ cnt_part,
                                                   double* __restrict__ ssum_part) {
  const int t = blockIdx.x * 256 + threadIdx.x;  // 0..8191
  const int b = t & (NBF - 1);
  const int c = t >> 11;                         // 0..3, 132 slices each
  const int s0 = c * (NSLICE / 4);
  unsigned int cs = 0;
  double ss = 0.0;
#pragma unroll 4
  for (int s = 0; s < NSLICE / 4; ++s) {
    const size_t off = (size_t)(s0 + s) * NBF + b;
    cs += slice_cnt[off];
    ss += (double)slice_ssum[off];
  }
  cnt_part[t] = cs;   // layout [c][b]
  ssum_part[t] = ss;
}

// ---- 4) finalize: prefix over bins, pick threshold bins, range sums ----
__global__ __launch_bounds__(256) void final_loss(const unsigned int* __restrict__ cnt_part,
                                                  const double* __restrict__ ssum_part,
                                                  const float* __restrict__ slice_top,
                                                  float* __restrict__ out,
                                                  unsigned int kneg, unsigned int kpos) {
  __shared__ unsigned int part[256], Q[256];
  __shared__ unsigned int sbp, sbn;
  __shared__ double tstage[4];
  __shared__ double dstage[2][4];
  __shared__ unsigned int ustage[2][4];
  const int tid = threadIdx.x;
  const int lane = tid & 63, wid = tid >> 6;

  // gather this thread's 8 bins (sum the 4 chunk partials; fixed order)
  unsigned int c8[8];
  double s8[8];
  unsigned int tot = 0;
#pragma unroll
  for (int j = 0; j < 8; ++j) {
    const int b = tid * 8 + j;
    unsigned int cc = 0;
    double ss = 0.0;
#pragma unroll
    for (int c = 0; c < 4; ++c) { cc += cnt_part[c * NBF + b]; ss += ssum_part[c * NBF + b]; }
    c8[j] = cc; s8[j] = ss; tot += cc;
  }
  // top-bin exact pos-term sum over slices
  {
    float tl = 0.f;
    for (int s = tid; s < NSLICE; s += 256) tl += slice_top[s];
    double td = tl;
#pragma unroll
    for (int o = 32; o > 0; o >>= 1) td += __shfl_xor(td, o);
    if (lane == 0) tstage[wid] = td;
  }
  // prefix scan over per-thread counts
  part[tid] = tot;
  Q[tid] = tot;
  __syncthreads();
#pragma unroll
  for (int off = 1; off < 256; off <<= 1) {
    unsigned int t2 = (tid >= off) ? Q[tid - off] : 0u;
    __syncthreads();
    Q[tid] += t2;
    __syncthreads();
  }
  const unsigned int total = Q[255];
  const unsigned int incl = Q[tid];
  const unsigned int excl = incl - part[tid];
  const unsigned int targets[2] = {kpos, kneg};
#pragma unroll
  for (int t = 0; t < 2; ++t) {
    const unsigned int r = (total == 0u) ? 0u
                         : (targets[t] < total ? targets[t] : total - 1u);
    if (total != 0u && excl <= r && r < incl) {  // exactly one owner
      unsigned int rr = r - excl, cum = 0;
      int bsel = -1;
#pragma unroll
      for (int j = 0; j < 8; ++j) {
        if (bsel < 0 && cum + c8[j] > rr) bsel = j;
        else if (bsel < 0) cum += c8[j];
      }
      if (bsel < 0) bsel = 7;
      if (t == 0) sbp = tid * 8 + (unsigned int)bsel;
      else        sbn = tid * 8 + (unsigned int)bsel;
    }
  }
  __syncthreads();
  const double topsum = tstage[0] + tstage[1] + tstage[2] + tstage[3];
  const unsigned int bp = sbp, bn = sbn;

  // range sums: pos over bins > bp, neg over bins < bn
  double psum = 0.0, nsum = 0.0;
  unsigned int pcnt = 0, ncnt = 0;
#pragma unroll
  for (int j = 0; j < 8; ++j) {
    const unsigned int b = tid * 8 + j;
    if (b > bp) {
      pcnt += c8[j];
      psum += (b == NBF - 1) ? topsum : ((double)c8[j] - s8[j]);  // sum fmax(1-s,0)
    }
    if (b < bn) {
      ncnt += c8[j];
      nsum += (b >= NBF / 2) ? s8[j] : 0.0;                       // sum fmax(s,0)
    }
  }
#pragma unroll
  for (int o = 32; o > 0; o >>= 1) {
    psum += __shfl_xor(psum, o);
    nsum += __shfl_xor(nsum, o);
    pcnt += __shfl_xor(pcnt, o);
    ncnt += __shfl_xor(ncnt, o);
  }
  if (lane == 0) {
    dstage[0][wid] = psum; dstage[1][wid] = nsum;
    ustage[0][wid] = pcnt; ustage[1][wid] = ncnt;
  }
  __syncthreads();
  if (tid == 0) {
    const double ps = dstage[0][0] + dstage[0][1] + dstage[0][2] + dstage[0][3];
    const double ns = dstage[1][0] + dstage[1][1] + dstage[1][2] + dstage[1][3];
    const unsigned int pc = ustage[0][0] + ustage[0][1] + ustage[0][2] + ustage[0][3];
    const unsigned int nc = ustage[1][0] + ustage[1][1] + ustage[1][2] + ustage[1][3];
    const double pl = pc ? ps / (double)pc : 0.0;
    const double nl = nc ? ns / (double)nc : 0.0;
    out[0] = (float)(pl + nl);
  }
}

extern "C" void kernel_launch(void* const* d_in, const int* in_sizes, int n_in,
                              void* d_out, int out_size, void* d_ws, size_t ws_size,
                              hipStream_t stream) {
  const float* x = (const float*)d_in[0];
  float* out = (float*)d_out;
  char* ws = (char*)d_ws;

  unsigned short* xnb = (unsigned short*)ws;                       // 4 MB
  size_t off = (size_t)N * D * 2;
  unsigned int* slice_cnt = (unsigned int*)(ws + off);             // 4.3 MB
  off += (size_t)NSLICE * NBF * 4;
  float* slice_ssum = (float*)(ws + off);                          // 4.3 MB
  off += (size_t)NSLICE * NBF * 4;
  float* slice_top = (float*)(ws + off);                           // 2.1 KB
  off += (size_t)NSLICE * 4;
  off = (off + 255) & ~(size_t)255;
  unsigned int* cnt_part = (unsigned int*)(ws + off);              // 32 KB
  off += (size_t)4 * NBF * 4;
  double* ssum_part = (double*)(ws + off);                         // 64 KB

  const unsigned int kneg = (unsigned int)ceil((double)NN * 0.2);          // 3355444
  const unsigned int kpos = (unsigned int)ceil((double)NN * (1.0 - 0.2));  // 13421773

  norm_conv<<<N, 256, 0, stream>>>(x, xnb);
  dim3 ggrid(N / BM, N / BM);  // upper-triangle blocks compute; lower exit
  gemm_fused<<<ggrid, 512, 0, stream>>>(xnb, slice_cnt, slice_ssum, slice_top);
  reduce_bins<<<32, 256, 0, stream>>>(slice_cnt, slice_ssum, cnt_part, ssum_part);
  final_loss<<<1, 256, 0, stream>>>(cnt_part, ssum_part, slice_top, out, kneg, kpos);
}

// Round 11
// 128.011 us; speedup vs baseline: 2.0637x; 1.0854x over previous
//
#include <hip/hip_runtime.h>
#include <hip/hip_bf16.h>
#include <math.h>

// AdaptiveContrastiveLoss: x[4096][512] f32 -> scalar f32.
// R10: K=512 is skinny (8 K-iters/tile) so 128^2-tile GEMM was all
// prologue/epilogue (110us @ MfmaUtil 3%). Moved to 256x256 tiles
// (HK geometry: 8 waves 2Mx4N, 128x64/wave, acc 8x4 frags): 136 blocks
// instead of 528, half the staging bytes per output, no dispatch tail.
// Bin-stats epilogue + reduce + final unchanged from R9 (absmax 0.0).
// ws: xnb 4MB | slice_cnt 1.1MB | slice_ssum 1.1MB | slice_top 544B |
//     cnt_part 32KB | ssum_part 64KB.

#define N 4096
#define D 512
#define NN 16777216u
#define NBF 2048         // uniform value bins
#define NSLICE 136       // upper-triangle 256x256 tiles of 4096^2

typedef __attribute__((ext_vector_type(8))) short bf16x8;
typedef __attribute__((ext_vector_type(4))) float f32x4;

// monotone value->bin: floor((s+1)*1024), clamped to [0, NBF-1].
// bin edge at s==0 is exact, so bin >= 1024 <=> s >= 0.
__device__ __forceinline__ int val2bin(float s) {
  int b = (int)fmaf(s, 1024.0f, 1024.0f);
  return b < 0 ? 0 : (b > NBF - 1 ? NBF - 1 : b);
}
__device__ __forceinline__ unsigned short f2bf(float f) {  // RNE
  unsigned int u = __float_as_uint(f);
  u += 0x7FFFu + ((u >> 16) & 1u);
  return (unsigned short)(u >> 16);
}

// ---- 1) row norms + normalize + f32->bf16 convert ----
__global__ __launch_bounds__(256) void norm_conv(const float* __restrict__ x,
                                                 unsigned short* __restrict__ xnb) {
  const int row = blockIdx.x;
  const int tid = threadIdx.x;
  const float2 v = ((const float2*)(x + (size_t)row * D))[tid];
  float s = v.x * v.x + v.y * v.y;
#pragma unroll
  for (int o = 32; o > 0; o >>= 1) s += __shfl_xor(s, o);
  __shared__ float wsum[4];
  __shared__ float s_rinv;
  if ((tid & 63) == 0) wsum[tid >> 6] = s;
  __syncthreads();
  if (tid == 0) {
    float t = wsum[0] + wsum[1] + wsum[2] + wsum[3];
    s_rinv = 1.0f / fmaxf(sqrtf(t), 1e-8f);
  }
  __syncthreads();
  const float r = s_rinv;
  ((ushort2*)(xnb + (size_t)row * D))[tid] = make_ushort2(f2bf(v.x * r), f2bf(v.y * r));
}

// ---- 2) fused GEMM + per-bin stats, 256x256 tile, 8 waves (2M x 4N) ----
#define BM 256
#define BK 64
#define LDK 72  // padded row stride (144B: 16B-aligned, 2-way-bank free)
__global__ __launch_bounds__(512, 2) void gemm_fused(const unsigned short* __restrict__ xnb,
                                                     unsigned int* __restrict__ slice_cnt,
                                                     float* __restrict__ slice_ssum,
                                                     float* __restrict__ slice_top) {
  const int bx = blockIdx.x, by = blockIdx.y;
  if (bx > by) return;  // lower-triangle tiles are bitwise mirrors of upper
  __shared__ unsigned short As[BM][LDK];
  __shared__ unsigned short Bs[BM][LDK];
  __shared__ unsigned int cnt[NBF];
  __shared__ float ssm[NBF];
  __shared__ float stop;  // exact sum of fmax(1-s,0) for top bin
  const int tid = threadIdx.x;
  for (int i = tid; i < NBF; i += 512) { cnt[i] = 0u; ssm[i] = 0.f; }
  if (tid == 0) stop = 0.f;

  const int w = tid >> 6, l = tid & 63;
  const int wr = w >> 2, wc = w & 3;       // wave grid 2M x 4N; wave = 128x64
  const int lr = l & 15, lk = (l >> 4) * 8;
  const int bm = bx * BM, bn = by * BM;

  f32x4 acc[8][4] = {};

  for (int kt = 0; kt < D; kt += BK) {
    // stage: A/B tiles 256x64 shorts = 2048 16B-chunks each; 4 chunks/thread
    bf16x8 av[4], bv[4];
#pragma unroll
    for (int q = 0; q < 4; ++q) {
      const int c = q * 512 + tid;
      const int row = c >> 3, off = (c & 7) * 8;
      av[q] = *(const bf16x8*)&xnb[(size_t)(bm + row) * D + kt + off];
      bv[q] = *(const bf16x8*)&xnb[(size_t)(bn + row) * D + kt + off];
    }
    __syncthreads();  // previous iter's LDS reads done (and bin init on iter 0)
#pragma unroll
    for (int q = 0; q < 4; ++q) {
      const int c = q * 512 + tid;
      const int row = c >> 3, off = (c & 7) * 8;
      *(bf16x8*)&As[row][off] = av[q];
      *(bf16x8*)&Bs[row][off] = bv[q];
    }
    __syncthreads();
#pragma unroll
    for (int kk = 0; kk < BK; kk += 32) {
      bf16x8 af[8], bf4[4];
#pragma unroll
      for (int m = 0; m < 8; ++m)
        af[m] = *(const bf16x8*)&As[wr * 128 + m * 16 + lr][kk + lk];
#pragma unroll
      for (int n = 0; n < 4; ++n)
        bf4[n] = *(const bf16x8*)&Bs[wc * 64 + n * 16 + lr][kk + lk];
#pragma unroll
      for (int m = 0; m < 8; ++m)
#pragma unroll
        for (int n = 0; n < 4; ++n)
          acc[m][n] = __builtin_amdgcn_mfma_f32_16x16x32_bf16(af[m], bf4[n], acc[m][n], 0, 0, 0);
    }
  }

  // epilogue: bin stats (only the value multiset matters)
  const unsigned int wg = (bx == by) ? 1u : 2u;
  const float fw = (float)wg;
  __syncthreads();
#pragma unroll
  for (int m = 0; m < 8; ++m)
#pragma unroll
    for (int n = 0; n < 4; ++n)
#pragma unroll
      for (int e = 0; e < 4; ++e) {
        const float s = acc[m][n][e];
        const int b = val2bin(s);
        atomicAdd(&cnt[b], wg);
        atomicAdd(&ssm[b], fw * s);
        if (b == NBF - 1) atomicAdd(&stop, fw * fmaxf(1.0f - s, 0.0f));
      }
  __syncthreads();
  // deterministic flush: plain stores to this block's private slice
  const int slice = by * (by + 1) / 2 + bx;
  unsigned int* oc = slice_cnt + (size_t)slice * NBF;
  float* os = slice_ssum + (size_t)slice * NBF;
  for (int i = tid; i < NBF; i += 512) { oc[i] = cnt[i]; os[i] = ssm[i]; }
  if (tid == 0) slice_top[slice] = stop;
}

// ---- 3) tree-reduce slices: 8192 threads, thread = (chunk c, bin b) ----
__global__ __launch_bounds__(256) void reduce_bins(const unsigned int* __restrict__ slice_cnt,
                                                   const float* __restrict__ slice_ssum,
                                                   unsigned int* __restrict__ cnt_part,
                                                   double* __restrict__ ssum_part) {
  const int t = blockIdx.x * 256 + threadIdx.x;  // 0..8191
  const int b = t & (NBF - 1);
  const int c = t >> 11;                         // 0..3, 34 slices each
  const int s0 = c * (NSLICE / 4);
  unsigned int cs = 0;
  double ss = 0.0;
#pragma unroll 4
  for (int s = 0; s < NSLICE / 4; ++s) {
    const size_t off = (size_t)(s0 + s) * NBF + b;
    cs += slice_cnt[off];
    ss += (double)slice_ssum[off];
  }
  cnt_part[t] = cs;   // layout [c][b]
  ssum_part[t] = ss;
}

// ---- 4) finalize: prefix over bins, pick threshold bins, range sums ----
__global__ __launch_bounds__(256) void final_loss(const unsigned int* __restrict__ cnt_part,
                                                  const double* __restrict__ ssum_part,
                                                  const float* __restrict__ slice_top,
                                                  float* __restrict__ out,
                                                  unsigned int kneg, unsigned int kpos) {
  __shared__ unsigned int part[256], Q[256];
  __shared__ unsigned int sbp, sbn;
  __shared__ double tstage[4];
  __shared__ double dstage[2][4];
  __shared__ unsigned int ustage[2][4];
  const int tid = threadIdx.x;
  const int lane = tid & 63, wid = tid >> 6;

  // gather this thread's 8 bins (sum the 4 chunk partials; fixed order)
  unsigned int c8[8];
  double s8[8];
  unsigned int tot = 0;
#pragma unroll
  for (int j = 0; j < 8; ++j) {
    const int b = tid * 8 + j;
    unsigned int cc = 0;
    double ss = 0.0;
#pragma unroll
    for (int c = 0; c < 4; ++c) { cc += cnt_part[c * NBF + b]; ss += ssum_part[c * NBF + b]; }
    c8[j] = cc; s8[j] = ss; tot += cc;
  }
  // top-bin exact pos-term sum over slices
  {
    float tl = 0.f;
    for (int s = tid; s < NSLICE; s += 256) tl += slice_top[s];
    double td = tl;
#pragma unroll
    for (int o = 32; o > 0; o >>= 1) td += __shfl_xor(td, o);
    if (lane == 0) tstage[wid] = td;
  }
  // prefix scan over per-thread counts
  part[tid] = tot;
  Q[tid] = tot;
  __syncthreads();
#pragma unroll
  for (int off = 1; off < 256; off <<= 1) {
    unsigned int t2 = (tid >= off) ? Q[tid - off] : 0u;
    __syncthreads();
    Q[tid] += t2;
    __syncthreads();
  }
  const unsigned int total = Q[255];
  const unsigned int incl = Q[tid];
  const unsigned int excl = incl - part[tid];
  const unsigned int targets[2] = {kpos, kneg};
#pragma unroll
  for (int t = 0; t < 2; ++t) {
    const unsigned int r = (total == 0u) ? 0u
                         : (targets[t] < total ? targets[t] : total - 1u);
    if (total != 0u && excl <= r && r < incl) {  // exactly one owner
      unsigned int rr = r - excl, cum = 0;
      int bsel = -1;
#pragma unroll
      for (int j = 0; j < 8; ++j) {
        if (bsel < 0 && cum + c8[j] > rr) bsel = j;
        else if (bsel < 0) cum += c8[j];
      }
      if (bsel < 0) bsel = 7;
      if (t == 0) sbp = tid * 8 + (unsigned int)bsel;
      else        sbn = tid * 8 + (unsigned int)bsel;
    }
  }
  __syncthreads();
  const double topsum = tstage[0] + tstage[1] + tstage[2] + tstage[3];
  const unsigned int bp = sbp, bn = sbn;

  // range sums: pos over bins > bp (sum fmax(1-s,0) = cnt - ssum there),
  // neg over bins < bn (sum fmax(s,0) = ssum for bins >= s=0 else 0)
  double psum = 0.0, nsum = 0.0;
  unsigned int pcnt = 0, ncnt = 0;
#pragma unroll
  for (int j = 0; j < 8; ++j) {
    const unsigned int b = tid * 8 + j;
    if (b > bp) {
      pcnt += c8[j];
      psum += (b == NBF - 1) ? topsum : ((double)c8[j] - s8[j]);
    }
    if (b < bn) {
      ncnt += c8[j];
      nsum += (b >= NBF / 2) ? s8[j] : 0.0;
    }
  }
#pragma unroll
  for (int o = 32; o > 0; o >>= 1) {
    psum += __shfl_xor(psum, o);
    nsum += __shfl_xor(nsum, o);
    pcnt += __shfl_xor(pcnt, o);
    ncnt += __shfl_xor(ncnt, o);
  }
  if (lane == 0) {
    dstage[0][wid] = psum; dstage[1][wid] = nsum;
    ustage[0][wid] = pcnt; ustage[1][wid] = ncnt;
  }
  __syncthreads();
  if (tid == 0) {
    const double ps = dstage[0][0] + dstage[0][1] + dstage[0][2] + dstage[0][3];
    const double ns = dstage[1][0] + dstage[1][1] + dstage[1][2] + dstage[1][3];
    const unsigned int pc = ustage[0][0] + ustage[0][1] + ustage[0][2] + ustage[0][3];
    const unsigned int nc = ustage[1][0] + ustage[1][1] + ustage[1][2] + ustage[1][3];
    const double pl = pc ? ps / (double)pc : 0.0;
    const double nl = nc ? ns / (double)nc : 0.0;
    out[0] = (float)(pl + nl);
  }
}

extern "C" void kernel_launch(void* const* d_in, const int* in_sizes, int n_in,
                              void* d_out, int out_size, void* d_ws, size_t ws_size,
                              hipStream_t stream) {
  const float* x = (const float*)d_in[0];
  float* out = (float*)d_out;
  char* ws = (char*)d_ws;

  unsigned short* xnb = (unsigned short*)ws;                       // 4 MB
  size_t off = (size_t)N * D * 2;
  unsigned int* slice_cnt = (unsigned int*)(ws + off);             // 1.11 MB
  off += (size_t)NSLICE * NBF * 4;
  float* slice_ssum = (float*)(ws + off);                          // 1.11 MB
  off += (size_t)NSLICE * NBF * 4;
  float* slice_top = (float*)(ws + off);                           // 544 B
  off += (size_t)NSLICE * 4;
  off = (off + 255) & ~(size_t)255;
  unsigned int* cnt_part = (unsigned int*)(ws + off);              // 32 KB
  off += (size_t)4 * NBF * 4;
  double* ssum_part = (double*)(ws + off);                         // 64 KB

  const unsigned int kneg = (unsigned int)ceil((double)NN * 0.2);          // 3355444
  const unsigned int kpos = (unsigned int)ceil((double)NN * (1.0 - 0.2));  // 13421773

  norm_conv<<<N, 256, 0, stream>>>(x, xnb);
  dim3 ggrid(N / BM, N / BM);  // 16x16; upper-triangle blocks compute
  gemm_fused<<<ggrid, 512, 0, stream>>>(xnb, slice_cnt, slice_ssum, slice_top);
  reduce_bins<<<32, 256, 0, stream>>>(slice_cnt, slice_ssum, cnt_part, ssum_part);
  final_loss<<<1, 256, 0, stream>>>(cnt_part, ssum_part, slice_top, out, kneg, kpos);
}